// Round 2
// baseline (754.146 us; speedup 1.0000x reference)
//
#include <hip/hip_runtime.h>
#include <hip/hip_fp16.h>

#define NN 40000
#define NE 640000
#define DD 128

typedef _Float16 half8 __attribute__((ext_vector_type(8)));
typedef float f32x4 __attribute__((ext_vector_type(4)));

__device__ __forceinline__ float silu_f(float x){
  // x * sigmoid(x); rcp is 1-ulp approx, fine for our tolerance
  return x * __builtin_amdgcn_rcpf(1.f + __expf(-x));
}

__device__ __forceinline__ half8 cvt_h8(float4 a, float4 b){
  half8 r;
  r[0]=(_Float16)a.x; r[1]=(_Float16)a.y; r[2]=(_Float16)a.z; r[3]=(_Float16)a.w;
  r[4]=(_Float16)b.x; r[5]=(_Float16)b.y; r[6]=(_Float16)b.z; r[7]=(_Float16)b.w;
  return r;
}

// packed f16 atomic add (no atomicAdd(__half2*) overload in this ROCm;
// the HW instruction exists — ISA §7)
__device__ __forceinline__ void atom_pk_f16(_Float16* p, unsigned v){
  asm volatile("global_atomic_pk_add_f16 %0, %1, off" :: "v"(p), "v"(v) : "memory");
}

// ---------------------------------------------------------------------------
// Edge kernel: fused phi_e (2 layers) + phi_x + scatter(agg, num, cnt)
// MFMA 16x16x32 f16. Layout facts used (guide §3, m89):
//   A-frag: row = lane&15, k = (lane>>4)*8 + j  (8 contiguous k)
//   B-frag: col = lane&15, k = (lane>>4)*8 + j
//   C/D   : col = lane&15, row = (lane>>4)*4 + reg
// Weights stored transposed in LDS: Wt[ch][k], elem offset ch*K + (k ^ ((ch&15)<<3))
// (per-16-lane phase: 8 distinct 16B slots x 2 rows -> 2-way aliasing = free, m136)
// ---------------------------------------------------------------------------
__global__ __launch_bounds__(256, 1)
void egnn_edge(const float* __restrict__ h, const float* __restrict__ x,
               const int* __restrict__ ei,
               const float* __restrict__ We1, const float* __restrict__ be1,
               const float* __restrict__ We2, const float* __restrict__ be2,
               const float* __restrict__ Wx1, const float* __restrict__ bx1,
               const float* __restrict__ Wx2, const float* __restrict__ bx2,
               _Float16* __restrict__ agg, float* __restrict__ numb,
               float* __restrict__ cnt)
{
  __shared__ _Float16 W1t[128*256];   // 64 KB  phi_e L1 (K=256, dist2 row folded out)
  __shared__ _Float16 W2t[128*128];   // 32 KB  phi_e L2
  __shared__ _Float16 Wxt[128*128];   // 32 KB  phi_x L1
  __shared__ _Float16 mbuf[4][16*128];// 16 KB  per-wave transpose buffer
  __shared__ int   ids_s[2][256];
  __shared__ float rel_s[3][256];
  __shared__ float d2_s[256];

  const int tid = threadIdx.x;
  for (int i = tid; i < 128*256; i += 256){
    int ch = i & 127, k = i >> 7;
    W1t[ch*256 + (k ^ ((ch & 15) << 3))] = (_Float16)We1[k*128 + ch];
  }
  for (int i = tid; i < 128*128; i += 256){
    int ch = i & 127, k = i >> 7;
    int sw = (ch & 15) << 3;
    W2t[ch*128 + (k ^ sw)] = (_Float16)We2[k*128 + ch];
    Wxt[ch*128 + (k ^ sw)] = (_Float16)Wx1[k*128 + ch];
  }
  const int lane = tid & 63;
  const int w    = tid >> 6;
  const int q    = lane & 15;
  const int g    = lane >> 4;
  float be1r[8], w1l[8], be2r[8], bx1r[8], wx2r[8];
  #pragma unroll
  for (int nt = 0; nt < 8; nt++){
    int ch = nt*16 + q;
    be1r[nt] = be1[ch];
    w1l[nt]  = We1[256*128 + ch];   // last row of We1 multiplies dist2
    be2r[nt] = be2[ch];
    bx1r[nt] = bx1[ch];
    wx2r[nt] = Wx2[ch];
  }
  const float bx2s = bx2[0];
  _Float16* mb = mbuf[w];
  const int eb = w*64;
  __syncthreads();

  for (int tile = blockIdx.x; tile < NE/256; tile += gridDim.x){
    const int base = tile * 256;
    __syncthreads();   // protect stage arrays from previous iteration's readers
    {
      int e = base + tid;
      int s = ei[e], d = ei[NE + e];
      ids_s[0][tid] = s; ids_s[1][tid] = d;
      float r0 = x[s*3+0] - x[d*3+0];
      float r1 = x[s*3+1] - x[d*3+1];
      float r2 = x[s*3+2] - x[d*3+2];
      rel_s[0][tid]=r0; rel_s[1][tid]=r1; rel_s[2][tid]=r2;
      d2_s[tid] = r0*r0 + r1*r1 + r2*r2;
    }
    __syncthreads();

    int srcid[4], dstid[4];
    #pragma unroll
    for (int mt=0; mt<4; mt++){
      srcid[mt] = ids_s[0][eb + mt*16 + q];
      dstid[mt] = ids_s[1][eb + mt*16 + q];
    }

    // ---- phi_e layer 1: e_in[256] @ We1 ----
    f32x4 acc1[4][8] = {};
    #pragma unroll
    for (int kk=0; kk<8; kk++){
      const int kh = (kk & 3)*32 + g*8;
      half8 a[4];
      #pragma unroll
      for (int mt=0; mt<4; mt++){
        const float* rp = h + (size_t)(kk<4 ? srcid[mt] : dstid[mt])*DD + kh;
        a[mt] = cvt_h8(*(const float4*)rp, *(const float4*)(rp+4));
      }
      #pragma unroll
      for (int nt=0; nt<8; nt++){
        half8 b = *(const half8*)&W1t[(nt*16+q)*256 + ((kk*32 + g*8) ^ (q<<3))];
        #pragma unroll
        for (int mt=0; mt<4; mt++)
          acc1[mt][nt] = __builtin_amdgcn_mfma_f32_16x16x32_f16(a[mt], b, acc1[mt][nt], 0,0,0);
      }
    }

    #pragma unroll
    for (int mt=0; mt<4; mt++){
      // bias (incl dist2 * last-row) + silu -> transpose into mbuf
      float d2v[4];
      #pragma unroll
      for (int r=0;r<4;r++) d2v[r] = d2_s[eb + mt*16 + 4*g + r];
      #pragma unroll
      for (int nt=0; nt<8; nt++){
        #pragma unroll
        for (int r=0;r<4;r++){
          float t = acc1[mt][nt][r] + be1r[nt] + d2v[r]*w1l[nt];
          float s = silu_f(t);
          int el = 4*g + r;
          mb[el*128 + ((nt*16+q) ^ (el<<3))] = (_Float16)s;
        }
      }
      // ---- phi_e layer 2 ----
      f32x4 acc2[8] = {};
      #pragma unroll
      for (int kk=0; kk<4; kk++){
        half8 am = *(const half8*)&mb[q*128 + ((kk*32+g*8) ^ (q<<3))];
        #pragma unroll
        for (int nt=0; nt<8; nt++){
          half8 b = *(const half8*)&W2t[(nt*16+q)*128 + ((kk*32+g*8) ^ (q<<3))];
          acc2[nt] = __builtin_amdgcn_mfma_f32_16x16x32_f16(am, b, acc2[nt], 0,0,0);
        }
      }
      // silu -> m, transpose into mbuf
      #pragma unroll
      for (int nt=0; nt<8; nt++){
        #pragma unroll
        for (int r=0;r<4;r++){
          float s = silu_f(acc2[nt][r] + be2r[nt]);
          int el = 4*g + r;
          mb[el*128 + ((nt*16+q) ^ (el<<3))] = (_Float16)s;
        }
      }
      // ---- phi_x layer 1 + agg scatter (packed f16 atomics on the same data) ----
      f32x4 acc3[8] = {};
      _Float16* aggrow = agg + (size_t)dstid[mt]*DD;
      #pragma unroll
      for (int kk=0; kk<4; kk++){
        uint4 raw = *(const uint4*)&mb[q*128 + ((kk*32+g*8) ^ (q<<3))];
        half8 am = __builtin_bit_cast(half8, raw);
        int k0 = kk*32 + g*8;
        atom_pk_f16(aggrow + k0 + 0, raw.x);
        atom_pk_f16(aggrow + k0 + 2, raw.y);
        atom_pk_f16(aggrow + k0 + 4, raw.z);
        atom_pk_f16(aggrow + k0 + 6, raw.w);
        #pragma unroll
        for (int nt=0; nt<8; nt++){
          half8 b = *(const half8*)&Wxt[(nt*16+q)*128 + ((kk*32+g*8) ^ (q<<3))];
          acc3[nt] = __builtin_amdgcn_mfma_f32_16x16x32_f16(am, b, acc3[nt], 0,0,0);
        }
      }
      // ---- coord_w = silu(.)@Wx2 + bx2, reduce over 128 ch, scatter num/cnt ----
      float part[4] = {0.f,0.f,0.f,0.f};
      #pragma unroll
      for (int nt=0; nt<8; nt++){
        #pragma unroll
        for (int r=0;r<4;r++)
          part[r] += silu_f(acc3[nt][r] + bx1r[nt]) * wx2r[nt];
      }
      #pragma unroll
      for (int m=1; m<16; m<<=1){
        #pragma unroll
        for (int r=0;r<4;r++) part[r] += __shfl_xor(part[r], m, 64);
      }
      if (q < 4){
        float cw = part[0];
        if (q==1) cw = part[1]; else if (q==2) cw = part[2]; else if (q==3) cw = part[3];
        cw += bx2s;
        int el = eb + mt*16 + 4*g + q;
        int dd = ids_s[1][el];
        unsafeAtomicAdd(numb + dd*3 + 0, rel_s[0][el]*cw);
        unsafeAtomicAdd(numb + dd*3 + 1, rel_s[1][el]*cw);
        unsafeAtomicAdd(numb + dd*3 + 2, rel_s[2][el]*cw);
        unsafeAtomicAdd(cnt + dd, 1.0f);
      }
    }
  }
}

// ---------------------------------------------------------------------------
// Node kernel: phi_h (2 layers) + residual + LayerNorm
// ---------------------------------------------------------------------------
__global__ __launch_bounds__(256, 1)
void egnn_node(const float* __restrict__ h, const _Float16* __restrict__ agg,
               const float* __restrict__ Wh1, const float* __restrict__ bh1,
               const float* __restrict__ Wh2, const float* __restrict__ bh2,
               const float* __restrict__ gam, const float* __restrict__ bet,
               float* __restrict__ hout)
{
  __shared__ _Float16 W1t[128*256];   // 64 KB
  __shared__ _Float16 W2t[128*128];   // 32 KB
  __shared__ _Float16 mbuf[4][16*128];// 16 KB
  const int tid = threadIdx.x;
  for (int i = tid; i < 128*256; i += 256){
    int ch = i & 127, k = i >> 7;
    W1t[ch*256 + (k ^ ((ch&15)<<3))] = (_Float16)Wh1[k*128 + ch];
  }
  for (int i = tid; i < 128*128; i += 256){
    int ch = i & 127, k = i >> 7;
    W2t[ch*128 + (k ^ ((ch&15)<<3))] = (_Float16)Wh2[k*128 + ch];
  }
  const int lane = tid & 63, w = tid>>6, q = lane&15, g = lane>>4;
  float bh1r[8], bh2r[8], gr[8], br[8];
  #pragma unroll
  for (int nt=0; nt<8; nt++){
    int ch = nt*16+q;
    bh1r[nt]=bh1[ch]; bh2r[nt]=bh2[ch]; gr[nt]=gam[ch]; br[nt]=bet[ch];
  }
  _Float16* mb = mbuf[w];
  __syncthreads();

  const int base = blockIdx.x*256 + w*64;

  f32x4 acc1[4][8] = {};
  #pragma unroll
  for (int kk=0; kk<8; kk++){
    half8 a[4];
    #pragma unroll
    for (int mt=0; mt<4; mt++){
      int node = base + mt*16 + q; if (node >= NN) node = NN-1;
      if (kk < 4){
        const float* rp = h + (size_t)node*DD + kk*32 + g*8;
        a[mt] = cvt_h8(*(const float4*)rp, *(const float4*)(rp+4));
      } else {
        a[mt] = *(const half8*)(agg + (size_t)node*DD + (kk-4)*32 + g*8);
      }
    }
    #pragma unroll
    for (int nt=0; nt<8; nt++){
      half8 b = *(const half8*)&W1t[(nt*16+q)*256 + ((kk*32+g*8) ^ (q<<3))];
      #pragma unroll
      for (int mt=0; mt<4; mt++)
        acc1[mt][nt] = __builtin_amdgcn_mfma_f32_16x16x32_f16(a[mt], b, acc1[mt][nt], 0,0,0);
    }
  }
  #pragma unroll
  for (int mt=0; mt<4; mt++){
    #pragma unroll
    for (int nt=0; nt<8; nt++){
      #pragma unroll
      for (int r=0;r<4;r++){
        float s = silu_f(acc1[mt][nt][r] + bh1r[nt]);
        int el = 4*g + r;
        mb[el*128 + ((nt*16+q) ^ (el<<3))] = (_Float16)s;
      }
    }
    f32x4 acc2[8] = {};
    #pragma unroll
    for (int kk=0; kk<4; kk++){
      half8 am = *(const half8*)&mb[q*128 + ((kk*32+g*8) ^ (q<<3))];
      #pragma unroll
      for (int nt=0; nt<8; nt++){
        half8 b = *(const half8*)&W2t[(nt*16+q)*128 + ((kk*32+g*8) ^ (q<<3))];
        acc2[nt] = __builtin_amdgcn_mfma_f32_16x16x32_f16(am, b, acc2[nt], 0,0,0);
      }
    }
    #pragma unroll
    for (int r=0;r<4;r++){
      int node = base + mt*16 + 4*g + r;
      int nid = node < NN ? node : NN-1;
      float hv[8]; float s1=0.f, s2=0.f;
      #pragma unroll
      for (int nt=0; nt<8; nt++){
        float v = acc2[nt][r] + bh2r[nt] + h[(size_t)nid*DD + nt*16 + q];
        hv[nt]=v; s1 += v; s2 += v*v;
      }
      #pragma unroll
      for (int m=1;m<16;m<<=1){ s1 += __shfl_xor(s1,m,64); s2 += __shfl_xor(s2,m,64); }
      float mu  = s1 * (1.f/128.f);
      float var = s2 * (1.f/128.f) - mu*mu;
      float rs  = rsqrtf(var + 1e-5f);
      if (node < NN){
        #pragma unroll
        for (int nt=0; nt<8; nt++)
          hout[(size_t)node*DD + nt*16 + q] = (hv[nt]-mu)*rs*gr[nt] + br[nt];
      }
    }
  }
}

__global__ void egnn_x(const float* __restrict__ x, const float* __restrict__ numb,
                       const float* __restrict__ cnt, float* __restrict__ xout){
  int i = blockIdx.x*256 + threadIdx.x;
  if (i < NN*3){
    int n = i/3;
    float c = cnt[n]; c = c > 1.f ? c : 1.f;
    xout[i] = x[i] + numb[i]*__builtin_amdgcn_rcpf(c);
  }
}

extern "C" void kernel_launch(void* const* d_in, const int* in_sizes, int n_in,
                              void* d_out, int out_size, void* d_ws, size_t ws_size,
                              hipStream_t stream){
  const float* h   = (const float*)d_in[0];
  const float* x   = (const float*)d_in[1];
  const int*   ei  = (const int*)d_in[2];
  // d_in[3] = vel (unused by reference output)
  const float* We1 = (const float*)d_in[4];
  const float* be1 = (const float*)d_in[5];
  const float* We2 = (const float*)d_in[6];
  const float* be2 = (const float*)d_in[7];
  const float* Wx1 = (const float*)d_in[8];
  const float* bx1 = (const float*)d_in[9];
  const float* Wx2 = (const float*)d_in[10];
  const float* bx2 = (const float*)d_in[11];
  const float* Wh1 = (const float*)d_in[12];
  const float* bh1 = (const float*)d_in[13];
  const float* Wh2 = (const float*)d_in[14];
  const float* bh2 = (const float*)d_in[15];
  const float* gam = (const float*)d_in[16];
  const float* bet = (const float*)d_in[17];

  float* hout = (float*)d_out;
  float* xout = hout + (size_t)NN*DD;

  _Float16* agg = (_Float16*)d_ws;                       // NN*128 f16 = 10.24 MB
  float* numb   = (float*)((char*)d_ws + (size_t)NN*DD*2); // NN*3 f32
  float* cnt    = numb + (size_t)NN*3;                     // NN f32
  size_t zero_bytes = (size_t)NN*DD*2 + (size_t)NN*3*4 + (size_t)NN*4;

  (void)hipMemsetAsync(d_ws, 0, zero_bytes, stream);
  egnn_edge<<<256, 256, 0, stream>>>(h, x, ei, We1, be1, We2, be2,
                                     Wx1, bx1, Wx2, bx2, agg, numb, cnt);
  egnn_node<<<(NN + 255)/256, 256, 0, stream>>>(h, agg, Wh1, bh1, Wh2, bh2,
                                                gam, bet, hout);
  egnn_x<<<(NN*3 + 255)/256, 256, 0, stream>>>(x, numb, cnt, xout);
}

// Round 3
// 418.754 us; speedup vs baseline: 1.8009x; 1.8009x over previous
//
#include <hip/hip_runtime.h>
#include <hip/hip_fp16.h>

#define NN 40000
#define NE 640000
#define DD 128

typedef _Float16 half8 __attribute__((ext_vector_type(8)));
typedef float f32x4 __attribute__((ext_vector_type(4)));

__device__ __forceinline__ float silu_f(float x){
  return x * __builtin_amdgcn_rcpf(1.f + __expf(-x));
}

__device__ __forceinline__ half8 cvt_h8(float4 a, float4 b){
  half8 r;
  r[0]=(_Float16)a.x; r[1]=(_Float16)a.y; r[2]=(_Float16)a.z; r[3]=(_Float16)a.w;
  r[4]=(_Float16)b.x; r[5]=(_Float16)b.y; r[6]=(_Float16)b.z; r[7]=(_Float16)b.w;
  return r;
}

__device__ __forceinline__ void atom_pk_f16(_Float16* p, unsigned v){
  asm volatile("global_atomic_pk_add_f16 %0, %1, off" :: "v"(p), "v"(v) : "memory");
}

// ---------------- sort-by-dst infrastructure ----------------
__global__ void k_hist(const int* __restrict__ ei, int* __restrict__ counts){
  int e = blockIdx.x*256 + threadIdx.x;
  if (e < NE) atomicAdd(&counts[ei[NE + e]], 1);
}

// single-block exclusive scan of counts[0..NN) -> woff
__global__ __launch_bounds__(1024)
void k_scan(const int* __restrict__ counts, int* __restrict__ woff){
  __shared__ int wsum[16];
  __shared__ int sbase;
  const int tid = threadIdx.x, lane = tid & 63, wv = tid >> 6;
  if (tid == 0) sbase = 0;
  __syncthreads();
  for (int c = 0; c < 40; ++c){
    int i = c*1024 + tid;
    int v = (i < NN) ? counts[i] : 0;
    int s = v;
    #pragma unroll
    for (int d = 1; d < 64; d <<= 1){
      int t = __shfl_up(s, d, 64);
      if (lane >= d) s += t;
    }
    if (lane == 63) wsum[wv] = s;
    __syncthreads();
    if (tid < 16){
      int t = wsum[tid];
      #pragma unroll
      for (int d = 1; d < 16; d <<= 1){
        int u = __shfl_up(t, d, 64);
        if (tid >= d) t += u;
      }
      wsum[tid] = t;
    }
    __syncthreads();
    int wbase = (wv == 0) ? 0 : wsum[wv-1];
    if (i < NN) woff[i] = sbase + wbase + s - v;   // exclusive
    __syncthreads();
    if (tid == 0) sbase += wsum[15];
    __syncthreads();
  }
}

__global__ void k_scatter(const int* __restrict__ ei, int* __restrict__ woff,
                          int* __restrict__ sid){
  int e = blockIdx.x*256 + threadIdx.x;
  if (e < NE){
    int d = ei[NE + e];
    int p = atomicAdd(&woff[d], 1);
    sid[p] = e;
  }
}

// ---------------------------------------------------------------------------
// Edge kernel over dst-sorted edges. 512 threads = 8 waves, no barriers in
// the tile loop (per-wave mbuf, register staging via shfl). Segment-reduced
// agg flush: f32 accumulate per channel-pair while dst unchanged, one
// pk-atomic per segment boundary.
// LDS: 64K W1t + 32K W2t + 32K Wxt + 8*4K mbuf = 163840 B (exact fit).
// ---------------------------------------------------------------------------
__global__ __launch_bounds__(512, 1)
void egnn_edge(const float* __restrict__ h, const float* __restrict__ x,
               const int* __restrict__ ei, const int* __restrict__ sid,
               const float* __restrict__ We1, const float* __restrict__ be1,
               const float* __restrict__ We2, const float* __restrict__ be2,
               const float* __restrict__ Wx1, const float* __restrict__ bx1,
               const float* __restrict__ Wx2, const float* __restrict__ bx2,
               _Float16* __restrict__ agg, float* __restrict__ numb)
{
  __shared__ __align__(16) _Float16 W1t[128*256];   // 64 KB
  __shared__ __align__(16) _Float16 W2t[128*128];   // 32 KB
  __shared__ __align__(16) _Float16 Wxt[128*128];   // 32 KB
  __shared__ __align__(16) _Float16 mbuf[8][16*128];// 32 KB

  const int tid = threadIdx.x;
  for (int i = tid; i < 128*256; i += 512){
    int ch = i & 127, k = i >> 7;
    W1t[ch*256 + (k ^ ((ch & 15) << 3))] = (_Float16)We1[k*128 + ch];
  }
  for (int i = tid; i < 128*128; i += 512){
    int ch = i & 127, k = i >> 7;
    int sw = (ch & 15) << 3;
    W2t[ch*128 + (k ^ sw)] = (_Float16)We2[k*128 + ch];
    Wxt[ch*128 + (k ^ sw)] = (_Float16)Wx1[k*128 + ch];
  }
  const int lane = tid & 63;
  const int w    = tid >> 6;
  const int q    = lane & 15;
  const int g    = lane >> 4;
  float be1r[8], w1l[8], be2r[8], bx1r[8], wx2r[8];
  #pragma unroll
  for (int nt = 0; nt < 8; nt++){
    int ch = nt*16 + q;
    be1r[nt] = be1[ch];
    w1l[nt]  = We1[256*128 + ch];   // last row of We1 multiplies dist2
    be2r[nt] = be2[ch];
    bx1r[nt] = bx1[ch];
    wx2r[nt] = Wx2[ch];
  }
  const float bx2s = bx2[0];
  _Float16* mb = mbuf[w];
  __syncthreads();

  for (int tile = blockIdx.x; tile < NE/512; tile += gridDim.x){
    // per-lane edge ownership: this wave's 64 edges, lane owns one
    const int eid  = sid[tile*512 + tid];
    const int esrc = ei[eid];
    const int edst = ei[NE + eid];
    float r0 = x[esrc*3+0] - x[edst*3+0];
    float r1 = x[esrc*3+1] - x[edst*3+1];
    float r2 = x[esrc*3+2] - x[edst*3+2];
    float d2 = r0*r0 + r1*r1 + r2*r2;

    int srcid[4], dstid[4];
    #pragma unroll
    for (int mt=0; mt<4; mt++){
      srcid[mt] = __shfl(esrc, mt*16 + q, 64);
      dstid[mt] = __shfl(edst, mt*16 + q, 64);
    }

    // ---- phi_e layer 1: e_in[256] @ We1 ----
    f32x4 acc1[4][8] = {};
    #pragma unroll
    for (int kk=0; kk<8; kk++){
      const int kh = (kk & 3)*32 + g*8;
      half8 a[4];
      #pragma unroll
      for (int mt=0; mt<4; mt++){
        const float* rp = h + (size_t)(kk<4 ? srcid[mt] : dstid[mt])*DD + kh;
        a[mt] = cvt_h8(*(const float4*)rp, *(const float4*)(rp+4));
      }
      #pragma unroll
      for (int nt=0; nt<8; nt++){
        half8 b = *(const half8*)&W1t[(nt*16+q)*256 + ((kk*32 + g*8) ^ (q<<3))];
        #pragma unroll
        for (int mt=0; mt<4; mt++)
          acc1[mt][nt] = __builtin_amdgcn_mfma_f32_16x16x32_f16(a[mt], b, acc1[mt][nt], 0,0,0);
      }
    }

    #pragma unroll
    for (int mt=0; mt<4; mt++){
      float d2v[4];
      #pragma unroll
      for (int r=0;r<4;r++) d2v[r] = __shfl(d2, mt*16 + 4*g + r, 64);
      #pragma unroll
      for (int nt=0; nt<8; nt++){
        #pragma unroll
        for (int r=0;r<4;r++){
          float t = acc1[mt][nt][r] + be1r[nt] + d2v[r]*w1l[nt];
          float s = silu_f(t);
          int el = 4*g + r;
          mb[el*128 + ((nt*16+q) ^ (el<<3))] = (_Float16)s;
        }
      }
      // ---- phi_e layer 2 ----
      f32x4 acc2[8] = {};
      #pragma unroll
      for (int kk=0; kk<4; kk++){
        half8 am = *(const half8*)&mb[q*128 + ((kk*32+g*8) ^ (q<<3))];
        #pragma unroll
        for (int nt=0; nt<8; nt++){
          half8 b = *(const half8*)&W2t[(nt*16+q)*128 + ((kk*32+g*8) ^ (q<<3))];
          acc2[nt] = __builtin_amdgcn_mfma_f32_16x16x32_f16(am, b, acc2[nt], 0,0,0);
        }
      }
      // silu -> m, transpose into mbuf
      #pragma unroll
      for (int nt=0; nt<8; nt++){
        #pragma unroll
        for (int r=0;r<4;r++){
          float s = silu_f(acc2[nt][r] + be2r[nt]);
          int el = 4*g + r;
          mb[el*128 + ((nt*16+q) ^ (el<<3))] = (_Float16)s;
        }
      }
      // ---- phi_x layer 1 (pure MFMA now) ----
      f32x4 acc3[8] = {};
      #pragma unroll
      for (int kk=0; kk<4; kk++){
        half8 am = *(const half8*)&mb[q*128 + ((kk*32+g*8) ^ (q<<3))];
        #pragma unroll
        for (int nt=0; nt<8; nt++){
          half8 b = *(const half8*)&Wxt[(nt*16+q)*128 + ((kk*32+g*8) ^ (q<<3))];
          acc3[nt] = __builtin_amdgcn_mfma_f32_16x16x32_f16(am, b, acc3[nt], 0,0,0);
        }
      }
      // ---- coord_w reduce + num scatter ----
      float part[4] = {0.f,0.f,0.f,0.f};
      #pragma unroll
      for (int nt=0; nt<8; nt++){
        #pragma unroll
        for (int r=0;r<4;r++)
          part[r] += silu_f(acc3[nt][r] + bx1r[nt]) * wx2r[nt];
      }
      #pragma unroll
      for (int m=1; m<16; m<<=1){
        #pragma unroll
        for (int r=0;r<4;r++) part[r] += __shfl_xor(part[r], m, 64);
      }
      {
        int elidx = mt*16 + 4*g + (q < 4 ? q : 3);
        int dd  = __shfl(edst, elidx, 64);
        float rr0 = __shfl(r0, elidx, 64);
        float rr1 = __shfl(r1, elidx, 64);
        float rr2 = __shfl(r2, elidx, 64);
        if (q < 4){
          float cw = part[0];
          if (q==1) cw = part[1]; else if (q==2) cw = part[2]; else if (q==3) cw = part[3];
          cw += bx2s;
          unsafeAtomicAdd(numb + dd*3 + 0, rr0*cw);
          unsafeAtomicAdd(numb + dd*3 + 1, rr1*cw);
          unsafeAtomicAdd(numb + dd*3 + 2, rr2*cw);
        }
      }
      // ---- segment-reduced agg flush: lane owns channel pair (2*lane, 2*lane+1)
      {
        float a0 = 0.f, a1 = 0.f;
        int dprev = __shfl(edst, mt*16, 64);
        #pragma unroll
        for (int e2=0; e2<16; e2++){
          int d = __shfl(edst, mt*16 + e2, 64);   // wave-uniform
          if (d != dprev){
            __half2 hv; hv.x = __float2half(a0); hv.y = __float2half(a1);
            atom_pk_f16(agg + (size_t)dprev*DD + 2*lane, __builtin_bit_cast(unsigned, hv));
            a0 = 0.f; a1 = 0.f; dprev = d;
          }
          unsigned u = *(const unsigned*)&mb[e2*128 + ((2*lane) ^ (e2<<3))];
          __half2 mv = __builtin_bit_cast(__half2, u);
          a0 += __half2float(mv.x);
          a1 += __half2float(mv.y);
        }
        __half2 hv; hv.x = __float2half(a0); hv.y = __float2half(a1);
        atom_pk_f16(agg + (size_t)dprev*DD + 2*lane, __builtin_bit_cast(unsigned, hv));
      }
    }
  }
}

// ---------------------------------------------------------------------------
// Node kernel: phi_h (2 layers) + residual + LayerNorm (unchanged)
// ---------------------------------------------------------------------------
__global__ __launch_bounds__(256, 1)
void egnn_node(const float* __restrict__ h, const _Float16* __restrict__ agg,
               const float* __restrict__ Wh1, const float* __restrict__ bh1,
               const float* __restrict__ Wh2, const float* __restrict__ bh2,
               const float* __restrict__ gam, const float* __restrict__ bet,
               float* __restrict__ hout)
{
  __shared__ __align__(16) _Float16 W1t[128*256];   // 64 KB
  __shared__ __align__(16) _Float16 W2t[128*128];   // 32 KB
  __shared__ __align__(16) _Float16 mbuf[4][16*128];// 16 KB
  const int tid = threadIdx.x;
  for (int i = tid; i < 128*256; i += 256){
    int ch = i & 127, k = i >> 7;
    W1t[ch*256 + (k ^ ((ch&15)<<3))] = (_Float16)Wh1[k*128 + ch];
  }
  for (int i = tid; i < 128*128; i += 256){
    int ch = i & 127, k = i >> 7;
    W2t[ch*128 + (k ^ ((ch&15)<<3))] = (_Float16)Wh2[k*128 + ch];
  }
  const int lane = tid & 63, w = tid>>6, q = lane&15, g = lane>>4;
  float bh1r[8], bh2r[8], gr[8], br[8];
  #pragma unroll
  for (int nt=0; nt<8; nt++){
    int ch = nt*16+q;
    bh1r[nt]=bh1[ch]; bh2r[nt]=bh2[ch]; gr[nt]=gam[ch]; br[nt]=bet[ch];
  }
  _Float16* mb = mbuf[w];
  __syncthreads();

  const int base = blockIdx.x*256 + w*64;

  f32x4 acc1[4][8] = {};
  #pragma unroll
  for (int kk=0; kk<8; kk++){
    half8 a[4];
    #pragma unroll
    for (int mt=0; mt<4; mt++){
      int node = base + mt*16 + q; if (node >= NN) node = NN-1;
      if (kk < 4){
        const float* rp = h + (size_t)node*DD + kk*32 + g*8;
        a[mt] = cvt_h8(*(const float4*)rp, *(const float4*)(rp+4));
      } else {
        a[mt] = *(const half8*)(agg + (size_t)node*DD + (kk-4)*32 + g*8);
      }
    }
    #pragma unroll
    for (int nt=0; nt<8; nt++){
      half8 b = *(const half8*)&W1t[(nt*16+q)*256 + ((kk*32+g*8) ^ (q<<3))];
      #pragma unroll
      for (int mt=0; mt<4; mt++)
        acc1[mt][nt] = __builtin_amdgcn_mfma_f32_16x16x32_f16(a[mt], b, acc1[mt][nt], 0,0,0);
    }
  }
  #pragma unroll
  for (int mt=0; mt<4; mt++){
    #pragma unroll
    for (int nt=0; nt<8; nt++){
      #pragma unroll
      for (int r=0;r<4;r++){
        float s = silu_f(acc1[mt][nt][r] + bh1r[nt]);
        int el = 4*g + r;
        mb[el*128 + ((nt*16+q) ^ (el<<3))] = (_Float16)s;
      }
    }
    f32x4 acc2[8] = {};
    #pragma unroll
    for (int kk=0; kk<4; kk++){
      half8 am = *(const half8*)&mb[q*128 + ((kk*32+g*8) ^ (q<<3))];
      #pragma unroll
      for (int nt=0; nt<8; nt++){
        half8 b = *(const half8*)&W2t[(nt*16+q)*128 + ((kk*32+g*8) ^ (q<<3))];
        acc2[nt] = __builtin_amdgcn_mfma_f32_16x16x32_f16(am, b, acc2[nt], 0,0,0);
      }
    }
    #pragma unroll
    for (int r=0;r<4;r++){
      int node = base + mt*16 + 4*g + r;
      int nid = node < NN ? node : NN-1;
      float hv[8]; float s1=0.f, s2=0.f;
      #pragma unroll
      for (int nt=0; nt<8; nt++){
        float v = acc2[nt][r] + bh2r[nt] + h[(size_t)nid*DD + nt*16 + q];
        hv[nt]=v; s1 += v; s2 += v*v;
      }
      #pragma unroll
      for (int m=1;m<16;m<<=1){ s1 += __shfl_xor(s1,m,64); s2 += __shfl_xor(s2,m,64); }
      float mu  = s1 * (1.f/128.f);
      float var = s2 * (1.f/128.f) - mu*mu;
      float rs  = rsqrtf(var + 1e-5f);
      if (node < NN){
        #pragma unroll
        for (int nt=0; nt<8; nt++)
          hout[(size_t)node*DD + nt*16 + q] = (hv[nt]-mu)*rs*gr[nt] + br[nt];
      }
    }
  }
}

__global__ void egnn_x(const float* __restrict__ x, const float* __restrict__ numb,
                       const int* __restrict__ cnt, float* __restrict__ xout){
  int i = blockIdx.x*256 + threadIdx.x;
  if (i < NN*3){
    int n = i/3;
    int c = cnt[n]; if (c < 1) c = 1;
    xout[i] = x[i] + numb[i]*__builtin_amdgcn_rcpf((float)c);
  }
}

extern "C" void kernel_launch(void* const* d_in, const int* in_sizes, int n_in,
                              void* d_out, int out_size, void* d_ws, size_t ws_size,
                              hipStream_t stream){
  const float* h   = (const float*)d_in[0];
  const float* x   = (const float*)d_in[1];
  const int*   ei  = (const int*)d_in[2];
  const float* We1 = (const float*)d_in[4];
  const float* be1 = (const float*)d_in[5];
  const float* We2 = (const float*)d_in[6];
  const float* be2 = (const float*)d_in[7];
  const float* Wx1 = (const float*)d_in[8];
  const float* bx1 = (const float*)d_in[9];
  const float* Wx2 = (const float*)d_in[10];
  const float* bx2 = (const float*)d_in[11];
  const float* Wh1 = (const float*)d_in[12];
  const float* bh1 = (const float*)d_in[13];
  const float* Wh2 = (const float*)d_in[14];
  const float* bh2 = (const float*)d_in[15];
  const float* gam = (const float*)d_in[16];
  const float* bet = (const float*)d_in[17];

  float* hout = (float*)d_out;
  float* xout = hout + (size_t)NN*DD;

  // ws layout (all 16B-aligned):
  char* p = (char*)d_ws;
  _Float16* agg = (_Float16*)p;                 p += (size_t)NN*DD*2;   // 10,240,000
  float* numb   = (float*)p;                    p += (size_t)NN*3*4;    //    480,000
  int* counts   = (int*)p;                      p += (size_t)NN*4;      //    160,000
  int* woff     = (int*)p;                      p += (size_t)NN*4;      //    160,000
  int* sid      = (int*)p;                                              // 2,560,000
  size_t zero_bytes = (size_t)NN*DD*2 + (size_t)NN*3*4 + (size_t)NN*4;  // agg+numb+counts

  (void)hipMemsetAsync(d_ws, 0, zero_bytes, stream);
  k_hist<<<(NE+255)/256, 256, 0, stream>>>(ei, counts);
  k_scan<<<1, 1024, 0, stream>>>(counts, woff);
  k_scatter<<<(NE+255)/256, 256, 0, stream>>>(ei, woff, sid);
  egnn_edge<<<250, 512, 0, stream>>>(h, x, ei, sid, We1, be1, We2, be2,
                                     Wx1, bx1, Wx2, bx2, agg, numb);
  egnn_node<<<(NN + 255)/256, 256, 0, stream>>>(h, agg, Wh1, bh1, Wh2, bh2,
                                                gam, bet, hout);
  egnn_x<<<(NN*3 + 255)/256, 256, 0, stream>>>(x, numb, counts, xout);
}